// Round 11
// baseline (349.365 us; speedup 1.0000x reference)
//
#include <hip/hip_runtime.h>

#define B_DIM 2048
#define IN_DIM 1024
#define M_DIM 256
#define P_DIM 32896            // 256*257/2
#define RTP_B 40960            // elements per batch: row-tile padded, chunk-XOR swizzled
#define CRTP_BYTES (167772160) // 2048*40960*2
#define WQ_BYTES   (33685504)  // 32896*1024 int8
#define XQ_BYTES   (2097152)   // 2048*1024 int8

typedef __attribute__((ext_vector_type(4)))  int   i32x4;
typedef __attribute__((ext_vector_type(4)))  float f32x4;
typedef __attribute__((ext_vector_type(8)))  short short8;

#define GLD16(gsrc, ldst) __builtin_amdgcn_global_load_lds(                    \
    (const __attribute__((address_space(1))) unsigned int*)(gsrc),             \
    (__attribute__((address_space(3))) unsigned int*)(ldst), 16, 0, 0)

__device__ __forceinline__ unsigned short f2bf(float f) {
    unsigned int u = __float_as_uint(f);
    u += 0x7FFFu + ((u >> 16) & 1u);          // RNE to bf16
    return (unsigned short)(u >> 16);
}
// base offset of row r: tile g padded to (g+1)*64 cols (rows 128B-aligned)
__device__ __forceinline__ int rtp0(int r) {
    const int g = r >> 6;
    return 2048 * g * (g + 1) + (r & 63) * ((g + 1) << 6);
}
// element (r,c): 8-el chunk index XOR'd by (r&7)
__device__ __forceinline__ int rtp_off(int r, int c) {
    return rtp0(r) + (((c >> 3) ^ (r & 7)) << 3) + (c & 7);
}

// ---------------- merged prep: W->i8 | X->i8 per-row scaled | Crtp pad zero ----------
#define NW_BLK 8224            // 8224*1024 float4 = 32896*1024/4
#define NX_BLK 512             // 4 rows/block (1 wave per row)
#define NZ_BLK 2048
__global__ void prep_all(const float* __restrict__ X, const float* __restrict__ W,
                         signed char* __restrict__ Xq, signed char* __restrict__ Wq,
                         float* __restrict__ Sx, unsigned short* __restrict__ Crtp) {
    const int bid = blockIdx.x, tid = threadIdx.x;
    if (bid < NW_BLK) {                         // W quant: wq = round(w*32*127), |w|<=1/32
#pragma unroll
        for (int u = 0; u < 4; ++u) {
            const int i = bid * 1024 + u * 256 + tid;       // float4 index
            float4 v = reinterpret_cast<const float4*>(W)[i];
            const int q0 = (int)rintf(v.x * 4064.f), q1 = (int)rintf(v.y * 4064.f);
            const int q2 = (int)rintf(v.z * 4064.f), q3 = (int)rintf(v.w * 4064.f);
            reinterpret_cast<unsigned int*>(Wq)[i] =
                (q0 & 255) | ((q1 & 255) << 8) | ((q2 & 255) << 16) | ((unsigned)(q3 & 255) << 24);
        }
    } else if (bid < NW_BLK + NX_BLK) {         // X quant, per-row scale
        const int wv  = tid >> 6, ln = tid & 63;
        const int row = (bid - NW_BLK) * 4 + wv;
        const float* xr = X + (size_t)row * IN_DIM + ln * 16;
        float f[16];
#pragma unroll
        for (int u = 0; u < 4; ++u) {
            float4 v = reinterpret_cast<const float4*>(xr)[u];
            f[u * 4 + 0] = v.x; f[u * 4 + 1] = v.y; f[u * 4 + 2] = v.z; f[u * 4 + 3] = v.w;
        }
        float m = 0.f;
#pragma unroll
        for (int e = 0; e < 16; ++e) m = fmaxf(m, fabsf(f[e]));
#pragma unroll
        for (int off = 1; off < 64; off <<= 1) m = fmaxf(m, __shfl_xor(m, off));
        const float inv = m > 1e-30f ? 127.f / m : 0.f;
        unsigned int w4[4];
#pragma unroll
        for (int u = 0; u < 4; ++u) {
            const int q0 = (int)rintf(f[u * 4 + 0] * inv), q1 = (int)rintf(f[u * 4 + 1] * inv);
            const int q2 = (int)rintf(f[u * 4 + 2] * inv), q3 = (int)rintf(f[u * 4 + 3] * inv);
            w4[u] = (q0 & 255) | ((q1 & 255) << 8) | ((q2 & 255) << 16) | ((unsigned)(q3 & 255) << 24);
        }
        reinterpret_cast<uint4*>(Xq + (size_t)row * IN_DIM)[ln] =
            make_uint4(w4[0], w4[1], w4[2], w4[3]);
        if (ln == 0) Sx[row] = m / (127.f * 4064.f);        // sx * sw combined
    } else {                                    // Crtp pad zero (layout unchanged)
        const int b = bid - NW_BLK - NX_BLK;
        const int r = tid;
        const int g = r >> 6;
        const int nch = (g + 1) << 3;
        const int xm = r & 7;
        unsigned short* base = Crtp + (size_t)b * RTP_B + rtp0(r);
        const int pc = (r >> 3) ^ xm;
        for (int c = r + 1; (c >> 3) == (r >> 3); ++c) base[(pc << 3) + (c & 7)] = 0;
        const uint4 z = make_uint4(0u, 0u, 0u, 0u);
        for (int cc = (r >> 3) + 1; cc < nch; ++cc)
            *reinterpret_cast<uint4*>(&base[(cc ^ xm) << 3]) = z;
    }
}

// ---------------- Stage 1: C = dequant(Xq @ Wq^T) + bias, diag-ReLU, rtp bf16 --------
// i8 MFMA 16x16x64. BM=256, BN=128, BK=64. 256 threads = 4 waves (2M x 2N),
// wave tile 128x64 = 8x4 frags -> 12 ds_read_b128 feed 32 MFMAs (was 8 feed 16).
// LDS chunk-XOR swizzle: physical 16B chunk = kq ^ ((row>>1)&3) -> 2-way banks (free).
// Triple-buffer ring (3 x 24KB = 72KB -> 2 blocks/CU), prefetch depth 2, counted
// vmcnt(6), 1 barrier/iter, setprio. Grid 2080 = R6's XCD mapping (measured best);
// 2056 live blocks / 512 slots = 4.01 rounds.
__global__ __launch_bounds__(256, 2) void gemm1_kernel(
    const signed char* __restrict__ Xq, const signed char* __restrict__ Wq,
    const float* __restrict__ bias, const float* __restrict__ Sx,
    unsigned short* __restrict__ Crtp)
{
    __shared__ __align__(16) unsigned char lds[3 * 24576];   // per buf: A 16KB | B 8KB

    const int lin = blockIdx.x;
    const int x   = lin & 7;                       // XCD (round-robin dispatch)
    const int j   = lin >> 3;                      // 0..259 within XCD
    const int rtile = ((x & 1) << 2) + (j & 3);    // 0..7
    const int panel = (x >> 1) * 65 + (j >> 2);    // 0..259
    if (panel >= 257) return;
    const int row0 = rtile << 8;
    const int col0 = panel << 7;

    const int tid  = threadIdx.x;
    const int lane = tid & 63;
    const int wid  = tid >> 6;                     // 0..3
    const int wr   = wid >> 1;                     // 0..1 (M half, 128 rows)
    const int wn   = wid & 1;                      // 0..1 (N half, 64 cols)
    const int lr16 = lane & 15;
    const int kq   = lane >> 4;                    // K 16B-chunk 0..3

    // staging: per K-tile wave stages A rows [64wid,+64) (4 GLD16) + B rows [32wid,+32)
    // (2 GLD16). lane -> row lane>>2, chunk lane&3; global chunk pre-XOR'd by (row>>1)&3
    // so linear LDS + swizzled read form a consistent involution.
    const int srow = lane >> 2;
    const signed char* gsA[4];
    const signed char* gsB[2];
#pragma unroll
    for (int i = 0; i < 4; ++i) {
        const int ra = (wid << 6) + (i << 4) + srow;              // block-local A row
        const int ch = (lane & 3) ^ ((ra >> 1) & 3);
        gsA[i] = Xq + (size_t)(row0 + ra) * IN_DIM + (ch << 4);
    }
#pragma unroll
    for (int i = 0; i < 2; ++i) {
        const int rb = (wid << 5) + (i << 4) + srow;              // block-local B row
        const int ch = (lane & 3) ^ ((rb >> 1) & 3);
        gsB[i] = Wq + (size_t)(col0 + rb) * IN_DIM + (ch << 4);
    }

#define STAGE(kt, bufo)                                                            \
    {                                                                              \
        GLD16(gsA[0] + ((kt) << 6), &lds[(bufo) + (wid << 12)]);                   \
        GLD16(gsA[1] + ((kt) << 6), &lds[(bufo) + (wid << 12) + 1024]);            \
        GLD16(gsA[2] + ((kt) << 6), &lds[(bufo) + (wid << 12) + 2048]);            \
        GLD16(gsA[3] + ((kt) << 6), &lds[(bufo) + (wid << 12) + 3072]);            \
        GLD16(gsB[0] + ((kt) << 6), &lds[(bufo) + 16384 + (wid << 11)]);           \
        GLD16(gsB[1] + ((kt) << 6), &lds[(bufo) + 16384 + (wid << 11) + 1024]);    \
    }

    i32x4 acc[8][4];
#pragma unroll
    for (int m = 0; m < 8; ++m)
#pragma unroll
        for (int n = 0; n < 4; ++n) acc[m][n] = (i32x4){0, 0, 0, 0};

    int o0 = 0, o1 = 24576, o2 = 49152;
    STAGE(0, o0);
    STAGE(1, o1);

    for (int it = 0; it < 16; ++it) {
        if (it < 15) asm volatile("s_waitcnt vmcnt(6)" ::: "memory");
        else         asm volatile("s_waitcnt vmcnt(0)" ::: "memory");
        __builtin_amdgcn_s_barrier();
        asm volatile("" ::: "memory");             // keep ds_reads below the barrier

        const int cb = o0;
        i32x4 av[8], bv[4];
#pragma unroll
        for (int m = 0; m < 8; ++m) {
            const int r = (wr << 7) + (m << 4) + lr16;
            av[m] = *reinterpret_cast<const i32x4*>(
                &lds[cb + (r << 6) + ((kq ^ ((r >> 1) & 3)) << 4)]);
        }
#pragma unroll
        for (int n = 0; n < 4; ++n) {
            const int r = (wn << 6) + (n << 4) + lr16;
            bv[n] = *reinterpret_cast<const i32x4*>(
                &lds[cb + 16384 + (r << 6) + ((kq ^ ((r >> 1) & 3)) << 4)]);
        }
        if (it < 14) STAGE(it + 2, o2);            // prefetch depth 2
        __builtin_amdgcn_s_setprio(1);
#pragma unroll
        for (int m = 0; m < 8; ++m)
#pragma unroll
            for (int n = 0; n < 4; ++n)
                acc[m][n] = __builtin_amdgcn_mfma_i32_16x16x64_i8(av[m], bv[n], acc[m][n], 0, 0, 0);
        __builtin_amdgcn_s_setprio(0);

        const int t = o0; o0 = o1; o1 = o2; o2 = t;   // rotate ring
    }
#undef STAGE

    // per-row dequant scales for this lane's 32 output rows
    float sc[8][4];
#pragma unroll
    for (int m = 0; m < 8; ++m)
#pragma unroll
        for (int q = 0; q < 4; ++q)
            sc[m][q] = Sx[row0 + (wr << 7) + (m << 4) + (kq << 2) + q];

    // epilogue: D col = lane&15, row = (lane>>4)*4 + reg
#pragma unroll
    for (int n = 0; n < 4; ++n) {
        const int p = col0 + (wn << 6) + (n << 4) + lr16;     // packed tril index
        const float t = sqrtf((float)(8 * p + 1));
        const int rt = (int)((t - 1.0f) * 0.5f + 0.001f);     // tril row
        const int ct = p - ((rt * (rt + 1)) >> 1);            // tril col
        const int off = rtp_off(rt, ct);                      // swizzled position
        const bool diag = (ct == rt);
        const float bvs = bias[p];
#pragma unroll
        for (int m = 0; m < 8; ++m) {
#pragma unroll
            for (int q = 0; q < 4; ++q) {
                const int brow = row0 + (wr << 7) + (m << 4) + (kq << 2) + q;
                float v = (float)acc[m][n][q] * sc[m][q] + bvs;
                if (diag) v = fmaxf(v, 0.f);
                Crtp[(size_t)brow * RTP_B + off] = f2bf(v);
            }
        }
    }
}

// ---------------- Stage 2: O[b] = L_b @ L_b^T, LDS-staged (80 KB -> 2 blocks/CU) ------
__global__ __launch_bounds__(256) void syrk_kernel(
    const unsigned short* __restrict__ Crtp, float* __restrict__ O)
{
    __shared__ unsigned short Lt[RTP_B];       // 81920 B exactly -> 2 blocks/CU
    const int tid  = threadIdx.x;
    const int lane = tid & 63;
    const int wid  = tid >> 6;
    const int b    = blockIdx.x;
    const unsigned short* Cb = Crtp + (size_t)b * RTP_B;

#pragma unroll
    for (int i = 0; i < 20; ++i) {
        const int g = wid * 20 + i;
        GLD16(Cb + g * 512 + (lane << 3), &Lt[g * 512]);
    }
    __syncthreads();

    const int lr16 = lane & 15;
    const int kc   = lane >> 4;
    float* Ob = O + (size_t)b * (M_DIM * M_DIM);

    const unsigned char LIST[4][5] = {
        {0x33, 0x22, 0x00, 0x00, 0x00},
        {0x23, 0x32, 0x01, 0x10, 0x00},
        {0x11, 0x12, 0x21, 0x02, 0x00},
        {0x13, 0x31, 0x03, 0x30, 0x20}};
    const int CNT[4] = {3, 4, 4, 5};
    const int cnt = CNT[wid];

    for (int tt = 0; tt < cnt; ++tt) {
        const int code = LIST[wid][tt];
        const int ti = code >> 4, tj = code & 15;

        int baseA[4], xA[4], baseB[4], xB[4];
#pragma unroll
        for (int m = 0; m < 4; ++m) {
            const int ia = (ti << 6) + (m << 4) + lr16;
            const int jb = (tj << 6) + (m << 4) + lr16;
            baseA[m] = rtp0(ia); xA[m] = ia & 7;
            baseB[m] = rtp0(jb); xB[m] = jb & 7;
        }
        f32x4 acc[4][4];
#pragma unroll
        for (int m = 0; m < 4; ++m)
#pragma unroll
            for (int n = 0; n < 4; ++n) acc[m][n] = (f32x4){0.f, 0.f, 0.f, 0.f};

        const int kmax = ti < tj ? ti : tj;
        for (int kt = 0; kt <= kmax; ++kt) {
#pragma unroll
            for (int s = 0; s < 2; ++s) {
                const int cidx = (kt << 3) + (s << 2) + kc;   // 8-el chunk index
                short8 a[4], bb[4];
#pragma unroll
                for (int m = 0; m < 4; ++m)
                    a[m] = *reinterpret_cast<const short8*>(&Lt[baseA[m] + ((cidx ^ xA[m]) << 3)]);
#pragma unroll
                for (int n = 0; n < 4; ++n)
                    bb[n] = *reinterpret_cast<const short8*>(&Lt[baseB[n] + ((cidx ^ xB[n]) << 3)]);
#pragma unroll
                for (int m = 0; m < 4; ++m)
#pragma unroll
                    for (int n = 0; n < 4; ++n)
                        acc[m][n] = __builtin_amdgcn_mfma_f32_16x16x32_bf16(a[m], bb[n], acc[m][n], 0, 0, 0);
            }
        }
#pragma unroll
        for (int m = 0; m < 4; ++m) {
            const int i0 = (ti << 6) + (m << 4) + (kc << 2);
#pragma unroll
            for (int n = 0; n < 4; ++n) {
                const int j = (tj << 6) + (n << 4) + lr16;
#pragma unroll
                for (int q = 0; q < 4; ++q)
                    __builtin_nontemporal_store(acc[m][n][q], &Ob[(size_t)(i0 + q) * M_DIM + j]);
            }
        }
    }
}

extern "C" void kernel_launch(void* const* d_in, const int* in_sizes, int n_in,
                              void* d_out, int out_size, void* d_ws, size_t ws_size,
                              hipStream_t stream)
{
    (void)in_sizes; (void)n_in; (void)out_size; (void)ws_size;
    const float* x    = (const float*)d_in[0];
    const float* W    = (const float*)d_in[1];
    const float* bias = (const float*)d_in[2];
    float* O = (float*)d_out;

    char* ws = (char*)d_ws;
    unsigned short* Crtp = (unsigned short*)ws;
    signed char*    Wq   = (signed char*)(ws + CRTP_BYTES);
    signed char*    Xq   = (signed char*)(ws + CRTP_BYTES + WQ_BYTES);
    float*          Sx   = (float*)(ws + CRTP_BYTES + WQ_BYTES + XQ_BYTES);

    prep_all<<<dim3(NW_BLK + NX_BLK + NZ_BLK), dim3(256), 0, stream>>>(
        x, W, Xq, Wq, Sx, Crtp);
    gemm1_kernel<<<dim3(2080), dim3(256), 0, stream>>>(Xq, Wq, bias, Sx, Crtp);
    syrk_kernel<<<dim3(B_DIM), dim3(256), 0, stream>>>(Crtp, O);
}

// Round 12
// 345.063 us; speedup vs baseline: 1.0125x; 1.0125x over previous
//
#include <hip/hip_runtime.h>

#define B_DIM 2048
#define IN_DIM 1024
#define M_DIM 256
#define P_DIM 32896            // 256*257/2
#define RTP_B 40960            // elements per batch: row-tile padded, chunk-XOR swizzled
#define CRTP_BYTES (167772160) // 2048*40960*2
#define WQ_BYTES   (33685504)  // 32896*1024 int8
#define XQ_BYTES   (2097152)   // 2048*1024 int8

typedef __attribute__((ext_vector_type(4)))  int   i32x4;
typedef __attribute__((ext_vector_type(4)))  float f32x4;
typedef __attribute__((ext_vector_type(8)))  short short8;

#define GLD16(gsrc, ldst) __builtin_amdgcn_global_load_lds(                    \
    (const __attribute__((address_space(1))) unsigned int*)(gsrc),             \
    (__attribute__((address_space(3))) unsigned int*)(ldst), 16, 0, 0)

__device__ __forceinline__ unsigned short f2bf(float f) {
    unsigned int u = __float_as_uint(f);
    u += 0x7FFFu + ((u >> 16) & 1u);          // RNE to bf16
    return (unsigned short)(u >> 16);
}
// base offset of row r: tile g padded to (g+1)*64 cols (rows 128B-aligned)
__device__ __forceinline__ int rtp0(int r) {
    const int g = r >> 6;
    return 2048 * g * (g + 1) + (r & 63) * ((g + 1) << 6);
}
// element (r,c): 8-el chunk index XOR'd by (r&7)
__device__ __forceinline__ int rtp_off(int r, int c) {
    return rtp0(r) + (((c >> 3) ^ (r & 7)) << 3) + (c & 7);
}

// ---------------- merged prep: W->i8 | X->i8 per-row scaled | Crtp pad zero ----------
#define NW_BLK 8224            // 8224*1024 float4 = 32896*1024/4
#define NX_BLK 512             // 4 rows/block (1 wave per row)
#define NZ_BLK 2048
__global__ void prep_all(const float* __restrict__ X, const float* __restrict__ W,
                         signed char* __restrict__ Xq, signed char* __restrict__ Wq,
                         float* __restrict__ Sx, unsigned short* __restrict__ Crtp) {
    const int bid = blockIdx.x, tid = threadIdx.x;
    if (bid < NW_BLK) {                         // W quant: wq = round(w*32*127), |w|<=1/32
#pragma unroll
        for (int u = 0; u < 4; ++u) {
            const int i = bid * 1024 + u * 256 + tid;       // float4 index
            float4 v = reinterpret_cast<const float4*>(W)[i];
            const int q0 = (int)rintf(v.x * 4064.f), q1 = (int)rintf(v.y * 4064.f);
            const int q2 = (int)rintf(v.z * 4064.f), q3 = (int)rintf(v.w * 4064.f);
            reinterpret_cast<unsigned int*>(Wq)[i] =
                (q0 & 255) | ((q1 & 255) << 8) | ((q2 & 255) << 16) | ((unsigned)(q3 & 255) << 24);
        }
    } else if (bid < NW_BLK + NX_BLK) {         // X quant, per-row scale
        const int wv  = tid >> 6, ln = tid & 63;
        const int row = (bid - NW_BLK) * 4 + wv;
        const float* xr = X + (size_t)row * IN_DIM + ln * 16;
        float f[16];
#pragma unroll
        for (int u = 0; u < 4; ++u) {
            float4 v = reinterpret_cast<const float4*>(xr)[u];
            f[u * 4 + 0] = v.x; f[u * 4 + 1] = v.y; f[u * 4 + 2] = v.z; f[u * 4 + 3] = v.w;
        }
        float m = 0.f;
#pragma unroll
        for (int e = 0; e < 16; ++e) m = fmaxf(m, fabsf(f[e]));
#pragma unroll
        for (int off = 1; off < 64; off <<= 1) m = fmaxf(m, __shfl_xor(m, off));
        const float inv = m > 1e-30f ? 127.f / m : 0.f;
        unsigned int w4[4];
#pragma unroll
        for (int u = 0; u < 4; ++u) {
            const int q0 = (int)rintf(f[u * 4 + 0] * inv), q1 = (int)rintf(f[u * 4 + 1] * inv);
            const int q2 = (int)rintf(f[u * 4 + 2] * inv), q3 = (int)rintf(f[u * 4 + 3] * inv);
            w4[u] = (q0 & 255) | ((q1 & 255) << 8) | ((q2 & 255) << 16) | ((unsigned)(q3 & 255) << 24);
        }
        reinterpret_cast<uint4*>(Xq + (size_t)row * IN_DIM)[ln] =
            make_uint4(w4[0], w4[1], w4[2], w4[3]);
        if (ln == 0) Sx[row] = m / (127.f * 4064.f);        // sx * sw combined
    } else {                                    // Crtp pad zero (layout unchanged)
        const int b = bid - NW_BLK - NX_BLK;
        const int r = tid;
        const int g = r >> 6;
        const int nch = (g + 1) << 3;
        const int xm = r & 7;
        unsigned short* base = Crtp + (size_t)b * RTP_B + rtp0(r);
        const int pc = (r >> 3) ^ xm;
        for (int c = r + 1; (c >> 3) == (r >> 3); ++c) base[(pc << 3) + (c & 7)] = 0;
        const uint4 z = make_uint4(0u, 0u, 0u, 0u);
        for (int cc = (r >> 3) + 1; cc < nch; ++cc)
            *reinterpret_cast<uint4*>(&base[(cc ^ xm) << 3]) = z;
    }
}

// ---------------- Stage 1: C = dequant(Xq @ Wq^T) + bias, diag-ReLU, rtp bf16 --------
// EXACT R10 structure (measured best, 334 us total): i8 MFMA 16x16x64, BM=256, BN=128,
// BK=64, 512 threads = 8 waves (4M x 2N), wave tile 64x64. Triple-buffer ring
// (3 x 24KB -> 2 blocks/CU, 16 waves/CU), prefetch depth 2, counted vmcnt(3),
// 1 barrier/iter, setprio. Linear chunks (b128 reads are at the 8-dword/bank floor —
// no swizzle needed; R11's swizzle+4-wave variant regressed via lost TLP).
__global__ __launch_bounds__(512) void gemm1_kernel(
    const signed char* __restrict__ Xq, const signed char* __restrict__ Wq,
    const float* __restrict__ bias, const float* __restrict__ Sx,
    unsigned short* __restrict__ Crtp)
{
    __shared__ __align__(16) unsigned char lds[3 * 24576];   // per buf: A 16KB | B 8KB

    const int lin = blockIdx.x;
    const int x   = lin & 7;                       // XCD (round-robin dispatch)
    const int j   = lin >> 3;                      // 0..259 within XCD
    const int rtile = ((x & 1) << 2) + (j & 3);    // 0..7
    const int panel = (x >> 1) * 65 + (j >> 2);    // 0..259
    if (panel >= 257) return;
    const int row0 = rtile << 8;
    const int col0 = panel << 7;

    const int tid  = threadIdx.x;
    const int lane = tid & 63;
    const int wid  = tid >> 6;                     // 0..7
    const int wr   = wid >> 1;                     // 0..3
    const int wc   = wid & 1;                      // 0..1
    const int lr16 = lane & 15;
    const int kq   = lane >> 4;                    // K-quarter 0..3

    const int srow = lane >> 2;
    const int sch  = lane & 3;
    const signed char* gA = Xq + (size_t)(row0 + (wid << 5) + srow) * IN_DIM + (sch << 4);
    const signed char* gB = Wq + (size_t)(col0 + (wid << 4) + srow) * IN_DIM + (sch << 4);

#define STAGE(kt, bufo)                                                          \
    {                                                                            \
        GLD16(gA + ((kt) << 6),                        &lds[(bufo) + (wid << 11)]); \
        GLD16(gA + (size_t)16 * IN_DIM + ((kt) << 6),  &lds[(bufo) + (wid << 11) + 1024]); \
        GLD16(gB + ((kt) << 6),                        &lds[(bufo) + 16384 + (wid << 10)]); \
    }

    i32x4 acc[4][4];
#pragma unroll
    for (int m = 0; m < 4; ++m)
#pragma unroll
        for (int n = 0; n < 4; ++n) acc[m][n] = (i32x4){0, 0, 0, 0};

    int o0 = 0, o1 = 24576, o2 = 49152;
    STAGE(0, o0);
    STAGE(1, o1);

    for (int it = 0; it < 16; ++it) {
        if (it < 15) asm volatile("s_waitcnt vmcnt(3)" ::: "memory");
        else         asm volatile("s_waitcnt vmcnt(0)" ::: "memory");
        __builtin_amdgcn_s_barrier();
        asm volatile("" ::: "memory");             // keep ds_reads below the barrier

        const int cb = o0;
        i32x4 av[4], bv[4];
#pragma unroll
        for (int m = 0; m < 4; ++m) {
            const int r = (wr << 6) + (m << 4) + lr16;
            av[m] = *reinterpret_cast<const i32x4*>(&lds[cb + (r << 6) + (kq << 4)]);
        }
#pragma unroll
        for (int n = 0; n < 4; ++n) {
            const int r = (wc << 6) + (n << 4) + lr16;
            bv[n] = *reinterpret_cast<const i32x4*>(&lds[cb + 16384 + (r << 6) + (kq << 4)]);
        }
        if (it < 14) STAGE(it + 2, o2);            // prefetch depth 2
        __builtin_amdgcn_s_setprio(1);
#pragma unroll
        for (int m = 0; m < 4; ++m)
#pragma unroll
            for (int n = 0; n < 4; ++n)
                acc[m][n] = __builtin_amdgcn_mfma_i32_16x16x64_i8(av[m], bv[n], acc[m][n], 0, 0, 0);
        __builtin_amdgcn_s_setprio(0);

        const int t = o0; o0 = o1; o1 = o2; o2 = t;   // rotate ring
    }
#undef STAGE

    // per-row dequant scales for this lane's 16 output rows
    float sc[4][4];
#pragma unroll
    for (int m = 0; m < 4; ++m)
#pragma unroll
        for (int q = 0; q < 4; ++q)
            sc[m][q] = Sx[row0 + (wr << 6) + (m << 4) + (kq << 2) + q];

    // epilogue: D col = lane&15, row = (lane>>4)*4 + reg
#pragma unroll
    for (int n = 0; n < 4; ++n) {
        const int p = col0 + (wc << 6) + (n << 4) + lr16;     // packed tril index
        const float t = sqrtf((float)(8 * p + 1));
        const int rt = (int)((t - 1.0f) * 0.5f + 0.001f);     // tril row
        const int ct = p - ((rt * (rt + 1)) >> 1);            // tril col
        const int off = rtp_off(rt, ct);                      // swizzled position
        const bool diag = (ct == rt);
        const float bvs = bias[p];
#pragma unroll
        for (int m = 0; m < 4; ++m) {
#pragma unroll
            for (int q = 0; q < 4; ++q) {
                const int brow = row0 + (wr << 6) + (m << 4) + (kq << 2) + q;
                float v = (float)acc[m][n][q] * sc[m][q] + bvs;
                if (diag) v = fmaxf(v, 0.f);
                Crtp[(size_t)brow * RTP_B + off] = f2bf(v);
            }
        }
    }
}

// ---------------- Stage 2: O[b] = L_b @ L_b^T, LDS-staged, 8-wave balanced ------------
// 512 threads = 8 waves; stage 80KB in 10 GLD16/wave (2x faster stage phase).
// Work = 20 half-jobs (ti,tj,mhalf): 2 m-frags x 4 n-frags, cost = min(ti,tj)+1.
// Packed perfectly 5/5/5/5/5/5/5/5 across waves (all static loop bounds, acc[2][4]).
// LDS 80KB -> 2 blocks/CU = 16 waves/CU.
__global__ __launch_bounds__(512) void syrk_kernel(
    const unsigned short* __restrict__ Crtp, float* __restrict__ O)
{
    __shared__ unsigned short Lt[RTP_B];       // 81920 B
    const int tid  = threadIdx.x;
    const int lane = tid & 63;
    const int wid  = tid >> 6;                 // 0..7
    const int b    = blockIdx.x;
    const unsigned short* Cb = Crtp + (size_t)b * RTP_B;

#pragma unroll
    for (int i = 0; i < 10; ++i) {
        const int g = wid * 10 + i;            // 0..79 x 1KiB segments
        GLD16(Cb + g * 512 + (lane << 3), &Lt[g * 512]);
    }
    __syncthreads();

    const int lr16 = lane & 15;
    const int kc   = lane >> 4;
    float* Ob = O + (size_t)b * (M_DIM * M_DIM);

    // code = (ti<<4)|(tj<<1)|mhalf ; per-wave cost = 5 units everywhere
    const unsigned char LIST[8][4] = {
        {0x36, 0x00, 0x00, 0x00},   // (3,3,0) (0,0,0)
        {0x37, 0x01, 0x00, 0x00},   // (3,3,1) (0,0,1)
        {0x34, 0x12, 0x00, 0x00},   // (3,2,0) (1,1,0)
        {0x35, 0x13, 0x00, 0x00},   // (3,2,1) (1,1,1)
        {0x24, 0x22, 0x00, 0x00},   // (2,2,0) (2,1,0)
        {0x25, 0x23, 0x00, 0x00},   // (2,2,1) (2,1,1)
        {0x32, 0x10, 0x20, 0x30},   // (3,1,0) (1,0,0) (2,0,0) (3,0,0)
        {0x33, 0x11, 0x21, 0x31}};  // (3,1,1) (1,0,1) (2,0,1) (3,0,1)
    const int CNT[8] = {2, 2, 2, 2, 2, 2, 4, 4};
    const int cnt = CNT[wid];

    for (int tt = 0; tt < cnt; ++tt) {
        const int c  = LIST[wid][tt];
        const int ti = c >> 4, tj = (c >> 1) & 7, mh = c & 1;
        const int ib = (ti << 6) + (mh << 5);          // first output row of this half

        int baseA[2], xA[2], baseB[4], xB[4];
#pragma unroll
        for (int m = 0; m < 2; ++m) {
            const int ia = ib + (m << 4) + lr16;
            baseA[m] = rtp0(ia); xA[m] = ia & 7;
        }
#pragma unroll
        for (int n = 0; n < 4; ++n) {
            const int jb = (tj << 6) + (n << 4) + lr16;
            baseB[n] = rtp0(jb); xB[n] = jb & 7;
        }
        f32x4 acc[2][4];
#pragma unroll
        for (int m = 0; m < 2; ++m)
#pragma unroll
            for (int n = 0; n < 4; ++n) acc[m][n] = (f32x4){0.f, 0.f, 0.f, 0.f};

        const int kmax = ti < tj ? ti : tj;
        for (int kt = 0; kt <= kmax; ++kt) {
#pragma unroll
            for (int s = 0; s < 2; ++s) {
                const int cidx = (kt << 3) + (s << 2) + kc;   // 8-el chunk index
                short8 a[2], bb[4];
#pragma unroll
                for (int m = 0; m < 2; ++m)
                    a[m] = *reinterpret_cast<const short8*>(&Lt[baseA[m] + ((cidx ^ xA[m]) << 3)]);
#pragma unroll
                for (int n = 0; n < 4; ++n)
                    bb[n] = *reinterpret_cast<const short8*>(&Lt[baseB[n] + ((cidx ^ xB[n]) << 3)]);
#pragma unroll
                for (int m = 0; m < 2; ++m)
#pragma unroll
                    for (int n = 0; n < 4; ++n)
                        acc[m][n] = __builtin_amdgcn_mfma_f32_16x16x32_bf16(a[m], bb[n], acc[m][n], 0, 0, 0);
            }
        }
#pragma unroll
        for (int m = 0; m < 2; ++m) {
            const int i0 = ib + (m << 4) + (kc << 2);
#pragma unroll
            for (int n = 0; n < 4; ++n) {
                const int jj = (tj << 6) + (n << 4) + lr16;
#pragma unroll
                for (int q = 0; q < 4; ++q)
                    __builtin_nontemporal_store(acc[m][n][q], &Ob[(size_t)(i0 + q) * M_DIM + jj]);
            }
        }
        if (ti != tj) {                                // mirror O[j][i] = O[i][j]
#pragma unroll
            for (int m = 0; m < 2; ++m) {
                const int i0 = ib + (m << 4) + (kc << 2);
#pragma unroll
                for (int n = 0; n < 4; ++n) {
                    const int jj = (tj << 6) + (n << 4) + lr16;
#pragma unroll
                    for (int q = 0; q < 4; ++q)
                        Ob[(size_t)jj * M_DIM + i0 + q] = acc[m][n][q];
                }
            }
        }
    }
}

extern "C" void kernel_launch(void* const* d_in, const int* in_sizes, int n_in,
                              void* d_out, int out_size, void* d_ws, size_t ws_size,
                              hipStream_t stream)
{
    (void)in_sizes; (void)n_in; (void)out_size; (void)ws_size;
    const float* x    = (const float*)d_in[0];
    const float* W    = (const float*)d_in[1];
    const float* bias = (const float*)d_in[2];
    float* O = (float*)d_out;

    char* ws = (char*)d_ws;
    unsigned short* Crtp = (unsigned short*)ws;
    signed char*    Wq   = (signed char*)(ws + CRTP_BYTES);
    signed char*    Xq   = (signed char*)(ws + CRTP_BYTES + WQ_BYTES);
    float*          Sx   = (float*)(ws + CRTP_BYTES + WQ_BYTES + XQ_BYTES);

    prep_all<<<dim3(NW_BLK + NX_BLK + NZ_BLK), dim3(256), 0, stream>>>(
        x, W, Xq, Wq, Sx, Crtp);
    gemm1_kernel<<<dim3(2080), dim3(512), 0, stream>>>(Xq, Wq, bias, Sx, Crtp);
    syrk_kernel<<<dim3(B_DIM), dim3(512), 0, stream>>>(Crtp, O);
}

// Round 13
// 331.379 us; speedup vs baseline: 1.0543x; 1.0413x over previous
//
#include <hip/hip_runtime.h>

#define B_DIM 2048
#define IN_DIM 1024
#define M_DIM 256
#define P_DIM 32896            // 256*257/2
#define RTP_B 40960            // elements per batch: row-tile padded, chunk-XOR swizzled
#define CRTP_BYTES (167772160) // 2048*40960*2
#define WQ_BYTES   (33685504)  // 32896*1024 int8
#define XQ_BYTES   (2097152)   // 2048*1024 int8

typedef __attribute__((ext_vector_type(4)))  int   i32x4;
typedef __attribute__((ext_vector_type(4)))  float f32x4;
typedef __attribute__((ext_vector_type(8)))  short short8;

#define GLD16(gsrc, ldst) __builtin_amdgcn_global_load_lds(                    \
    (const __attribute__((address_space(1))) unsigned int*)(gsrc),             \
    (__attribute__((address_space(3))) unsigned int*)(ldst), 16, 0, 0)

__device__ __forceinline__ unsigned short f2bf(float f) {
    unsigned int u = __float_as_uint(f);
    u += 0x7FFFu + ((u >> 16) & 1u);          // RNE to bf16
    return (unsigned short)(u >> 16);
}
// base offset of row r: tile g padded to (g+1)*64 cols (rows 128B-aligned)
__device__ __forceinline__ int rtp0(int r) {
    const int g = r >> 6;
    return 2048 * g * (g + 1) + (r & 63) * ((g + 1) << 6);
}
// element (r,c): 8-el chunk index XOR'd by (r&7)
__device__ __forceinline__ int rtp_off(int r, int c) {
    return rtp0(r) + (((c >> 3) ^ (r & 7)) << 3) + (c & 7);
}

// ---------------- merged prep: W->i8 | X->i8 per-row scaled | Crtp pad zero ----------
#define NW_BLK 8224            // 8224*1024 float4 = 32896*1024/4
#define NX_BLK 512             // 4 rows/block (1 wave per row)
#define NZ_BLK 2048
__global__ void prep_all(const float* __restrict__ X, const float* __restrict__ W,
                         signed char* __restrict__ Xq, signed char* __restrict__ Wq,
                         float* __restrict__ Sx, unsigned short* __restrict__ Crtp) {
    const int bid = blockIdx.x, tid = threadIdx.x;
    if (bid < NW_BLK) {                         // W quant: wq = round(w*32*127), |w|<=1/32
#pragma unroll
        for (int u = 0; u < 4; ++u) {
            const int i = bid * 1024 + u * 256 + tid;       // float4 index
            float4 v = reinterpret_cast<const float4*>(W)[i];
            const int q0 = (int)rintf(v.x * 4064.f), q1 = (int)rintf(v.y * 4064.f);
            const int q2 = (int)rintf(v.z * 4064.f), q3 = (int)rintf(v.w * 4064.f);
            reinterpret_cast<unsigned int*>(Wq)[i] =
                (q0 & 255) | ((q1 & 255) << 8) | ((q2 & 255) << 16) | ((unsigned)(q3 & 255) << 24);
        }
    } else if (bid < NW_BLK + NX_BLK) {         // X quant, per-row scale
        const int wv  = tid >> 6, ln = tid & 63;
        const int row = (bid - NW_BLK) * 4 + wv;
        const float* xr = X + (size_t)row * IN_DIM + ln * 16;
        float f[16];
#pragma unroll
        for (int u = 0; u < 4; ++u) {
            float4 v = reinterpret_cast<const float4*>(xr)[u];
            f[u * 4 + 0] = v.x; f[u * 4 + 1] = v.y; f[u * 4 + 2] = v.z; f[u * 4 + 3] = v.w;
        }
        float m = 0.f;
#pragma unroll
        for (int e = 0; e < 16; ++e) m = fmaxf(m, fabsf(f[e]));
#pragma unroll
        for (int off = 1; off < 64; off <<= 1) m = fmaxf(m, __shfl_xor(m, off));
        const float inv = m > 1e-30f ? 127.f / m : 0.f;
        unsigned int w4[4];
#pragma unroll
        for (int u = 0; u < 4; ++u) {
            const int q0 = (int)rintf(f[u * 4 + 0] * inv), q1 = (int)rintf(f[u * 4 + 1] * inv);
            const int q2 = (int)rintf(f[u * 4 + 2] * inv), q3 = (int)rintf(f[u * 4 + 3] * inv);
            w4[u] = (q0 & 255) | ((q1 & 255) << 8) | ((q2 & 255) << 16) | ((unsigned)(q3 & 255) << 24);
        }
        reinterpret_cast<uint4*>(Xq + (size_t)row * IN_DIM)[ln] =
            make_uint4(w4[0], w4[1], w4[2], w4[3]);
        if (ln == 0) Sx[row] = m / (127.f * 4064.f);        // sx * sw combined
    } else {                                    // Crtp pad zero (layout unchanged)
        const int b = bid - NW_BLK - NX_BLK;
        const int r = tid;
        const int g = r >> 6;
        const int nch = (g + 1) << 3;
        const int xm = r & 7;
        unsigned short* base = Crtp + (size_t)b * RTP_B + rtp0(r);
        const int pc = (r >> 3) ^ xm;
        for (int c = r + 1; (c >> 3) == (r >> 3); ++c) base[(pc << 3) + (c & 7)] = 0;
        const uint4 z = make_uint4(0u, 0u, 0u, 0u);
        for (int cc = (r >> 3) + 1; cc < nch; ++cc)
            *reinterpret_cast<uint4*>(&base[(cc ^ xm) << 3]) = z;
    }
}

// ---------------- Stage 1: C = dequant(Xq @ Wq^T) + bias, diag-ReLU, rtp bf16 --------
// EXACT R10 structure (measured best): i8 MFMA 16x16x64, BM=256, BN=128, BK=64,
// 512 threads = 8 waves (4M x 2N), wave tile 64x64. Triple-buffer ring
// (3 x 24KB -> 2 blocks/CU, 16 waves/CU), prefetch depth 2, counted vmcnt(3),
// 1 barrier/iter, setprio. Linear chunks (b128 at the 8-dword/bank floor).
__global__ __launch_bounds__(512) void gemm1_kernel(
    const signed char* __restrict__ Xq, const signed char* __restrict__ Wq,
    const float* __restrict__ bias, const float* __restrict__ Sx,
    unsigned short* __restrict__ Crtp)
{
    __shared__ __align__(16) unsigned char lds[3 * 24576];   // per buf: A 16KB | B 8KB

    const int lin = blockIdx.x;
    const int x   = lin & 7;                       // XCD (round-robin dispatch)
    const int j   = lin >> 3;                      // 0..259 within XCD
    const int rtile = ((x & 1) << 2) + (j & 3);    // 0..7
    const int panel = (x >> 1) * 65 + (j >> 2);    // 0..259
    if (panel >= 257) return;
    const int row0 = rtile << 8;
    const int col0 = panel << 7;

    const int tid  = threadIdx.x;
    const int lane = tid & 63;
    const int wid  = tid >> 6;                     // 0..7
    const int wr   = wid >> 1;                     // 0..3
    const int wc   = wid & 1;                      // 0..1
    const int lr16 = lane & 15;
    const int kq   = lane >> 4;                    // K-quarter 0..3

    const int srow = lane >> 2;
    const int sch  = lane & 3;
    const signed char* gA = Xq + (size_t)(row0 + (wid << 5) + srow) * IN_DIM + (sch << 4);
    const signed char* gB = Wq + (size_t)(col0 + (wid << 4) + srow) * IN_DIM + (sch << 4);

#define STAGE(kt, bufo)                                                          \
    {                                                                            \
        GLD16(gA + ((kt) << 6),                        &lds[(bufo) + (wid << 11)]); \
        GLD16(gA + (size_t)16 * IN_DIM + ((kt) << 6),  &lds[(bufo) + (wid << 11) + 1024]); \
        GLD16(gB + ((kt) << 6),                        &lds[(bufo) + 16384 + (wid << 10)]); \
    }

    i32x4 acc[4][4];
#pragma unroll
    for (int m = 0; m < 4; ++m)
#pragma unroll
        for (int n = 0; n < 4; ++n) acc[m][n] = (i32x4){0, 0, 0, 0};

    int o0 = 0, o1 = 24576, o2 = 49152;
    STAGE(0, o0);
    STAGE(1, o1);

    for (int it = 0; it < 16; ++it) {
        if (it < 15) asm volatile("s_waitcnt vmcnt(3)" ::: "memory");
        else         asm volatile("s_waitcnt vmcnt(0)" ::: "memory");
        __builtin_amdgcn_s_barrier();
        asm volatile("" ::: "memory");             // keep ds_reads below the barrier

        const int cb = o0;
        i32x4 av[4], bv[4];
#pragma unroll
        for (int m = 0; m < 4; ++m) {
            const int r = (wr << 6) + (m << 4) + lr16;
            av[m] = *reinterpret_cast<const i32x4*>(&lds[cb + (r << 6) + (kq << 4)]);
        }
#pragma unroll
        for (int n = 0; n < 4; ++n) {
            const int r = (wc << 6) + (n << 4) + lr16;
            bv[n] = *reinterpret_cast<const i32x4*>(&lds[cb + 16384 + (r << 6) + (kq << 4)]);
        }
        if (it < 14) STAGE(it + 2, o2);            // prefetch depth 2
        __builtin_amdgcn_s_setprio(1);
#pragma unroll
        for (int m = 0; m < 4; ++m)
#pragma unroll
            for (int n = 0; n < 4; ++n)
                acc[m][n] = __builtin_amdgcn_mfma_i32_16x16x64_i8(av[m], bv[n], acc[m][n], 0, 0, 0);
        __builtin_amdgcn_s_setprio(0);

        const int t = o0; o0 = o1; o1 = o2; o2 = t;   // rotate ring
    }
#undef STAGE

    // per-row dequant scales for this lane's 16 output rows
    float sc[4][4];
#pragma unroll
    for (int m = 0; m < 4; ++m)
#pragma unroll
        for (int q = 0; q < 4; ++q)
            sc[m][q] = Sx[row0 + (wr << 6) + (m << 4) + (kq << 2) + q];

    // epilogue: D col = lane&15, row = (lane>>4)*4 + reg
#pragma unroll
    for (int n = 0; n < 4; ++n) {
        const int p = col0 + (wc << 6) + (n << 4) + lr16;     // packed tril index
        const float t = sqrtf((float)(8 * p + 1));
        const int rt = (int)((t - 1.0f) * 0.5f + 0.001f);     // tril row
        const int ct = p - ((rt * (rt + 1)) >> 1);            // tril col
        const int off = rtp_off(rt, ct);                      // swizzled position
        const bool diag = (ct == rt);
        const float bvs = bias[p];
#pragma unroll
        for (int m = 0; m < 4; ++m) {
#pragma unroll
            for (int q = 0; q < 4; ++q) {
                const int brow = row0 + (wr << 6) + (m << 4) + (kq << 2) + q;
                float v = (float)acc[m][n][q] * sc[m][q] + bvs;
                if (diag) v = fmaxf(v, 0.f);
                Crtp[(size_t)brow * RTP_B + off] = f2bf(v);
            }
        }
    }
}

// ---------------- Stage 2: O[b] = L_b @ L_b^T, LDS-staged, 512 threads ---------------
// Full-square 16 whole tiles (ALL stores coalesced, no mirror scatter — R12's mistake).
// 8 waves: stage = 10 GLD16/wave (half of R10); tile costs (min(ti,tj)+1, total 30)
// packed max-4 per wave (R10 was max-5): w0..w7 = 4/4/4/4/4/4/4/2.
// LDS 80KB -> 2 blocks/CU = 16 waves/CU during compute.
__global__ __launch_bounds__(512) void syrk_kernel(
    const unsigned short* __restrict__ Crtp, float* __restrict__ O)
{
    __shared__ unsigned short Lt[RTP_B];       // 81920 B
    const int tid  = threadIdx.x;
    const int lane = tid & 63;
    const int wid  = tid >> 6;                 // 0..7
    const int b    = blockIdx.x;
    const unsigned short* Cb = Crtp + (size_t)b * RTP_B;

#pragma unroll
    for (int i = 0; i < 10; ++i) {
        const int g = wid * 10 + i;            // 80 x 1KiB segments
        GLD16(Cb + g * 512 + (lane << 3), &Lt[g * 512]);
    }
    __syncthreads();

    const int lr16 = lane & 15;
    const int kc   = lane >> 4;
    float* Ob = O + (size_t)b * (M_DIM * M_DIM);

    // code = (ti<<4)|tj ; per-wave k-unit cost: 4/4/4/4/4/4/4/2
    const unsigned char LIST[8][3] = {
        {0x33, 0x00, 0x00},   // (3,3)
        {0x22, 0x00, 0x00},   // (2,2) (0,0)
        {0x23, 0x01, 0x00},   // (2,3) (0,1)
        {0x32, 0x02, 0x00},   // (3,2) (0,2)
        {0x11, 0x12, 0x00},   // (1,1) (1,2)
        {0x21, 0x13, 0x00},   // (2,1) (1,3)
        {0x31, 0x10, 0x20},   // (3,1) (1,0) (2,0)
        {0x30, 0x03, 0x00}};  // (3,0) (0,3)
    const int CNT[8] = {1, 2, 2, 2, 2, 2, 3, 2};
    const int cnt = CNT[wid];

    for (int tt = 0; tt < cnt; ++tt) {
        const int code = LIST[wid][tt];
        const int ti = code >> 4, tj = code & 15;

        int baseA[4], xA[4], baseB[4], xB[4];
#pragma unroll
        for (int m = 0; m < 4; ++m) {
            const int ia = (ti << 6) + (m << 4) + lr16;
            const int jb = (tj << 6) + (m << 4) + lr16;
            baseA[m] = rtp0(ia); xA[m] = ia & 7;
            baseB[m] = rtp0(jb); xB[m] = jb & 7;
        }
        f32x4 acc[4][4];
#pragma unroll
        for (int m = 0; m < 4; ++m)
#pragma unroll
            for (int n = 0; n < 4; ++n) acc[m][n] = (f32x4){0.f, 0.f, 0.f, 0.f};

        const int kmax = ti < tj ? ti : tj;
        for (int kt = 0; kt <= kmax; ++kt) {
#pragma unroll
            for (int s = 0; s < 2; ++s) {
                const int cidx = (kt << 3) + (s << 2) + kc;   // 8-el chunk index
                short8 a[4], bb[4];
#pragma unroll
                for (int m = 0; m < 4; ++m)
                    a[m] = *reinterpret_cast<const short8*>(&Lt[baseA[m] + ((cidx ^ xA[m]) << 3)]);
#pragma unroll
                for (int n = 0; n < 4; ++n)
                    bb[n] = *reinterpret_cast<const short8*>(&Lt[baseB[n] + ((cidx ^ xB[n]) << 3)]);
#pragma unroll
                for (int m = 0; m < 4; ++m)
#pragma unroll
                    for (int n = 0; n < 4; ++n)
                        acc[m][n] = __builtin_amdgcn_mfma_f32_16x16x32_bf16(a[m], bb[n], acc[m][n], 0, 0, 0);
            }
        }
#pragma unroll
        for (int m = 0; m < 4; ++m) {
            const int i0 = (ti << 6) + (m << 4) + (kc << 2);
#pragma unroll
            for (int n = 0; n < 4; ++n) {
                const int j = (tj << 6) + (n << 4) + lr16;
#pragma unroll
                for (int q = 0; q < 4; ++q)
                    __builtin_nontemporal_store(acc[m][n][q], &Ob[(size_t)(i0 + q) * M_DIM + j]);
            }
        }
    }
}

extern "C" void kernel_launch(void* const* d_in, const int* in_sizes, int n_in,
                              void* d_out, int out_size, void* d_ws, size_t ws_size,
                              hipStream_t stream)
{
    (void)in_sizes; (void)n_in; (void)out_size; (void)ws_size;
    const float* x    = (const float*)d_in[0];
    const float* W    = (const float*)d_in[1];
    const float* bias = (const float*)d_in[2];
    float* O = (float*)d_out;

    char* ws = (char*)d_ws;
    unsigned short* Crtp = (unsigned short*)ws;
    signed char*    Wq   = (signed char*)(ws + CRTP_BYTES);
    signed char*    Xq   = (signed char*)(ws + CRTP_BYTES + WQ_BYTES);
    float*          Sx   = (float*)(ws + CRTP_BYTES + WQ_BYTES + XQ_BYTES);

    prep_all<<<dim3(NW_BLK + NX_BLK + NZ_BLK), dim3(256), 0, stream>>>(
        x, W, Xq, Wq, Sx, Crtp);
    gemm1_kernel<<<dim3(2080), dim3(512), 0, stream>>>(Xq, Wq, bias, Sx, Crtp);
    syrk_kernel<<<dim3(B_DIM), dim3(512), 0, stream>>>(Crtp, O);
}